// Round 7
// baseline (105.605 us; speedup 1.0000x reference)
//
#include <hip/hip_runtime.h>

#define SGRID 32
#define SGRID3 (SGRID * SGRID * SGRID)   // 32768 cells
#define Q5 (31.0f / 32.0f)               // quantize scale
#define DQ5 (32.0f / 31.0f)              // dequantize scale

// ------- prep: quantize closest -> 5:5:5 u16, build affine mats, zero out ----
__global__ __launch_bounds__(256)
void prep_kernel(const float* __restrict__ output,
                 const float* __restrict__ closest,
                 unsigned short* __restrict__ tbl,   // B * 32768 u16
                 float* __restrict__ mats,           // B * 72
                 float* __restrict__ out,
                 int B) {
    int tid = blockIdx.x * blockDim.x + threadIdx.x;
    int total = B * SGRID3;
    int base = tid * 4;
    if (base + 3 < total) {
        const float4* src = (const float4*)closest;  // 4 cells = 12 floats
        float4 a = src[(size_t)tid * 3 + 0];
        float4 b = src[(size_t)tid * 3 + 1];
        float4 c = src[(size_t)tid * 3 + 2];
        float cx[4] = {a.x, a.w, b.z, c.y};
        float cy[4] = {a.y, b.x, b.w, c.z};
        float cz[4] = {a.z, b.y, c.x, c.w};
        ushort4 q;
        unsigned short* qp = (unsigned short*)&q;
#pragma unroll
        for (int k = 0; k < 4; k++) {
            unsigned int qx = min((unsigned int)(fmaxf(cx[k], 0.f) * Q5 + 0.5f), 31u);
            unsigned int qy = min((unsigned int)(fmaxf(cy[k], 0.f) * Q5 + 0.5f), 31u);
            unsigned int qz = min((unsigned int)(fmaxf(cz[k], 0.f) * Q5 + 0.5f), 31u);
            qp[k] = (unsigned short)(qx | (qy << 5) | (qz << 10));
        }
        *((ushort4*)(tbl + base)) = q;
    }
    if (blockIdx.x == 0) {
        if (threadIdx.x == 0) out[0] = 0.f;
        if (threadIdx.x < B * 6) {
            int b = threadIdx.x / 6, i = threadIdx.x % 6;
            const float* p = output + b * 24 + i * 4;
            float m[12];
            if (i < 3) {
                float a = p[0], bb = p[1], c = p[2], d = p[3];
                float k = -2.f / (a * a + bb * bb + c * c);
                m[0] = 1.f + k * a * a;  m[1] = k * a * bb;        m[2] = k * a * c;        m[3] = k * d * a;
                m[4] = k * bb * a;       m[5] = 1.f + k * bb * bb; m[6] = k * bb * c;       m[7] = k * d * bb;
                m[8] = k * c * a;        m[9] = k * c * bb;        m[10] = 1.f + k * c * c; m[11] = k * d * c;
            } else {
                float w = p[0], x = p[1], y = p[2], z = p[3];
                float s = rsqrtf(w * w + x * x + y * y + z * z);
                m[0] = s * (w * w + x * x - y * y - z * z);
                m[1] = s * 2.f * (x * y - w * z);
                m[2] = s * 2.f * (x * z + w * y);
                m[3] = 0.f;
                m[4] = s * 2.f * (x * y + w * z);
                m[5] = s * (w * w - x * x + y * y - z * z);
                m[6] = s * 2.f * (y * z - w * x);
                m[7] = 0.f;
                m[8] = s * 2.f * (x * z - w * y);
                m[9] = s * 2.f * (y * z + w * x);
                m[10] = s * (w * w - x * x - y * y + z * z);
                m[11] = 0.f;
            }
            float* dst = mats + (size_t)threadIdx.x * 12;
#pragma unroll
            for (int j = 0; j < 12; j++) dst[j] = m[j];
        }
    }
}

// ------- main: 64 KB u16 LDS table, 2 blocks/CU, 24-deep gather batches -----
// block=256 => VGPR budget 256 even at 2 blocks/CU: no spill risk (R4 lesson).
// All 24 gathers (4 pts x 6 ops) issued before any decode: max lgkm overlap.
__global__ __launch_bounds__(256)
void sym_loss_v7(const unsigned short* __restrict__ tbl,
                 const float* __restrict__ mats,
                 const float* __restrict__ points,
                 float* __restrict__ out,
                 int N, int B, int bpb, float invB) {
    __shared__ unsigned short sT[SGRID3];   // 64 KB
    __shared__ float sred[4];

    const int i = blockIdx.x;
    int b, x;
    if (B == 16 && (gridDim.x & 15) == 0) {
        // XCD swizzle: block i lands on XCD i%8 -> 2 batches per XCD in L2
        b = 2 * (i & 7) + ((i >> 3) & 1);
        x = i >> 4;
    } else {
        b = i / bpb;
        x = i - b * bpb;
    }

    // stage 64 KB: 4096 uint4 across 256 threads = 16 x 16B each
    {
        const uint4* src = (const uint4*)(tbl + (size_t)b * SGRID3);
        uint4* dst = (uint4*)sT;
#pragma unroll
        for (int j = 0; j < 16; j++)
            dst[j * 256 + threadIdx.x] = src[j * 256 + threadIdx.x];
    }

    // wave-uniform affine mats (6 x 3x4) -> SGPRs
    const float* mb = mats + (size_t)b * 72;
    float M[72];
#pragma unroll
    for (int j = 0; j < 72; j++) M[j] = mb[j];

    __syncthreads();

    const float* pb = points + (size_t)b * N * 3;
    const float4* pv = (const float4*)pb;
    float acc = 0.f;

    // one quad (4 consecutive points = 3 float4) per thread
    const int q = x * (int)blockDim.x + (int)threadIdx.x;
    const int base = q * 4;
    if (base + 3 < N) {
        float4 v0 = pv[(size_t)q * 3 + 0];
        float4 v1 = pv[(size_t)q * 3 + 1];
        float4 v2 = pv[(size_t)q * 3 + 2];
        float px[4] = {v0.x, v0.w, v1.z, v2.y};
        float py[4] = {v0.y, v1.x, v1.w, v2.z};
        float pz[4] = {v0.z, v1.y, v2.x, v2.w};

        float sx[24], sy[24], sz[24];
        unsigned short g[24];
        // phase 1: all 24 transforms + addresses + gathers issued
#pragma unroll
        for (int k = 0; k < 4; k++) {
            float X = px[k], Y = py[k], Z = pz[k];
#pragma unroll
            for (int op = 0; op < 6; op++) {
                int j = k * 6 + op;
                const float* m = &M[op * 12];
                sx[j] = fmaf(m[0], X, fmaf(m[1], Y, fmaf(m[2], Z, m[3])));
                sy[j] = fmaf(m[4], X, fmaf(m[5], Y, fmaf(m[6], Z, m[7])));
                sz[j] = fmaf(m[8], X, fmaf(m[9], Y, fmaf(m[10], Z, m[11])));
                int ix = min(max((int)sx[j], 0), 31);   // v_cvt + v_med3_i32
                int iy = min(max((int)sy[j], 0), 31);
                int iz = min(max((int)sz[j], 0), 31);
                g[j] = sT[(ix << 10) | (iy << 5) | iz];
            }
        }
        // phase 2: decode + distance
#pragma unroll
        for (int j = 0; j < 24; j++) {
            unsigned int gg = g[j];
            float gx = (float)(gg & 31u);
            float gy = (float)((gg >> 5) & 31u);
            float gz = (float)(gg >> 10);
            float dx = fmaf(-DQ5, gx, sx[j]);
            float dy = fmaf(-DQ5, gy, sy[j]);
            float dz = fmaf(-DQ5, gz, sz[j]);
            acc += __builtin_amdgcn_sqrtf(fmaf(dx, dx, fmaf(dy, dy, dz * dz)));
        }
    } else if (base < N) {
        for (int k = 0; k < N - base; k++) {
            float X = pb[(size_t)(base + k) * 3 + 0];
            float Y = pb[(size_t)(base + k) * 3 + 1];
            float Z = pb[(size_t)(base + k) * 3 + 2];
#pragma unroll
            for (int op = 0; op < 6; op++) {
                const float* m = &M[op * 12];
                float ssx = fmaf(m[0], X, fmaf(m[1], Y, fmaf(m[2], Z, m[3])));
                float ssy = fmaf(m[4], X, fmaf(m[5], Y, fmaf(m[6], Z, m[7])));
                float ssz = fmaf(m[8], X, fmaf(m[9], Y, fmaf(m[10], Z, m[11])));
                int ix = min(max((int)ssx, 0), 31);
                int iy = min(max((int)ssy, 0), 31);
                int iz = min(max((int)ssz, 0), 31);
                unsigned int gg = sT[(ix << 10) | (iy << 5) | iz];
                float gx = (float)(gg & 31u);
                float gy = (float)((gg >> 5) & 31u);
                float gz = (float)(gg >> 10);
                float dx = fmaf(-DQ5, gx, ssx);
                float dy = fmaf(-DQ5, gy, ssy);
                float dz = fmaf(-DQ5, gz, ssz);
                acc += __builtin_amdgcn_sqrtf(fmaf(dx, dx, fmaf(dy, dy, dz * dz)));
            }
        }
    }

    // reduce: wave64 shuffle -> LDS -> one atomic per block
#pragma unroll
    for (int off = 32; off > 0; off >>= 1)
        acc += __shfl_down(acc, off, 64);

    int lane = threadIdx.x & 63;
    int wid = threadIdx.x >> 6;
    if (lane == 0) sred[wid] = acc;
    __syncthreads();
    if (threadIdx.x == 0) {
        atomicAdd(out, (sred[0] + sred[1] + sred[2] + sred[3]) * invB);
    }
}

// ------- fallback (ws too small): direct-gather kernel ----------------------
__global__ void zero_out_kernel(float* out) { out[0] = 0.0f; }

__launch_bounds__(256)
__global__ void sym_loss_kernel(const float* __restrict__ output,
                                const float* __restrict__ points,
                                const float* __restrict__ closest,
                                float* __restrict__ out,
                                int N, float invB) {
    const int b = blockIdx.y;
    const int tid = blockIdx.x * blockDim.x + threadIdx.x;
    const float* prm = output + (size_t)b * 24;
    float pn[3][4], inv_nn[3], qt[3][4], qinvn[3];
#pragma unroll
    for (int i = 0; i < 3; i++) {
        pn[i][0] = prm[i * 4 + 0]; pn[i][1] = prm[i * 4 + 1];
        pn[i][2] = prm[i * 4 + 2]; pn[i][3] = prm[i * 4 + 3];
        inv_nn[i] = 1.0f / (pn[i][0] * pn[i][0] + pn[i][1] * pn[i][1] + pn[i][2] * pn[i][2]);
        qt[i][0] = prm[12 + i * 4 + 0]; qt[i][1] = prm[12 + i * 4 + 1];
        qt[i][2] = prm[12 + i * 4 + 2]; qt[i][3] = prm[12 + i * 4 + 3];
        qinvn[i] = rsqrtf(qt[i][0] * qt[i][0] + qt[i][1] * qt[i][1] +
                          qt[i][2] * qt[i][2] + qt[i][3] * qt[i][3]);
    }
    const float* pb = points + (size_t)b * N * 3;
    const float* cb = closest + (size_t)b * SGRID3 * 3;
    float acc = 0.0f;
    const int base = tid * 4;
    float px[4], py[4], pz[4];
    int npts = 0;
    if (base + 3 < N) {
        const float4* pv = (const float4*)pb;
        float4 v0 = pv[(size_t)tid * 3 + 0];
        float4 v1 = pv[(size_t)tid * 3 + 1];
        float4 v2 = pv[(size_t)tid * 3 + 2];
        px[0] = v0.x; py[0] = v0.y; pz[0] = v0.z;
        px[1] = v0.w; py[1] = v1.x; pz[1] = v1.y;
        px[2] = v1.z; py[2] = v1.w; pz[2] = v2.x;
        px[3] = v2.y; py[3] = v2.z; pz[3] = v2.w;
        npts = 4;
    } else if (base < N) {
        npts = N - base;
        for (int k = 0; k < npts; k++) {
            px[k] = pb[(size_t)(base + k) * 3 + 0];
            py[k] = pb[(size_t)(base + k) * 3 + 1];
            pz[k] = pb[(size_t)(base + k) * 3 + 2];
        }
    }
#pragma unroll
    for (int k = 0; k < 4; k++) {
        if (k >= npts) break;
        float x = px[k], y = py[k], z = pz[k];
#pragma unroll
        for (int i = 0; i < 3; i++) {
            float nx = pn[i][0], ny = pn[i][1], nz = pn[i][2];
            float dis = (nx * x + ny * y + nz * z + pn[i][3]) * inv_nn[i];
            float t = 2.0f * dis;
            float sx = x - t * nx, sy = y - t * ny, sz = z - t * nz;
            int ix = min(max((int)fminf(sx, 32.f), 0), 31);
            int iy = min(max((int)fminf(sy, 32.f), 0), 31);
            int iz = min(max((int)fminf(sz, 32.f), 0), 31);
            const float* c = cb + (size_t)((ix << 10) | (iy << 5) | iz) * 3;
            float dx = sx - c[0], dy = sy - c[1], dz = sz - c[2];
            acc += __builtin_amdgcn_sqrtf(fmaf(dx, dx, fmaf(dy, dy, dz * dz)));
        }
#pragma unroll
        for (int i = 0; i < 3; i++) {
            float rw = qt[i][0], rx = qt[i][1], ry = qt[i][2], rz = qt[i][3];
            float tw = -(rx * x + ry * y + rz * z);
            float tx = rw * x + (ry * z - rz * y);
            float ty = rw * y + (rz * x - rx * z);
            float tz = rw * z + (rx * y - ry * x);
            float n = qinvn[i];
            float ox = (-tw * rx + rw * tx + (ry * tz - rz * ty)) * n;
            float oy = (-tw * ry + rw * ty + (rz * tx - rx * tz)) * n;
            float oz = (-tw * rz + rw * tz + (rx * ty - ry * tx)) * n;
            int ix = min(max((int)fminf(ox, 32.f), 0), 31);
            int iy = min(max((int)fminf(oy, 32.f), 0), 31);
            int iz = min(max((int)fminf(oz, 32.f), 0), 31);
            const float* c = cb + (size_t)((ix << 10) | (iy << 5) | iz) * 3;
            float dx = ox - c[0], dy = oy - c[1], dz = oz - c[2];
            acc += __builtin_amdgcn_sqrtf(fmaf(dx, dx, fmaf(dy, dy, dz * dz)));
        }
    }
#pragma unroll
    for (int off = 32; off > 0; off >>= 1)
        acc += __shfl_down(acc, off, 64);
    __shared__ float sacc[4];
    int lane = threadIdx.x & 63;
    int wid = threadIdx.x >> 6;
    if (lane == 0) sacc[wid] = acc;
    __syncthreads();
    if (threadIdx.x == 0)
        atomicAdd(out, (sacc[0] + sacc[1] + sacc[2] + sacc[3]) * invB);
}

extern "C" void kernel_launch(void* const* d_in, const int* in_sizes, int n_in,
                              void* d_out, int out_size, void* d_ws, size_t ws_size,
                              hipStream_t stream) {
    const float* output = (const float*)d_in[0];
    const float* points = (const float*)d_in[1];
    const float* closest = (const float*)d_in[2];
    float* out = (float*)d_out;

    int B = in_sizes[0] / 24;
    int N = in_sizes[1] / (3 * B);

    size_t tbl_bytes = (size_t)B * SGRID3 * 2;
    size_t mats_bytes = (size_t)B * 72 * 4;

    if (ws_size >= tbl_bytes + mats_bytes) {
        unsigned short* tbl = (unsigned short*)d_ws;
        float* mats = (float*)((char*)d_ws + tbl_bytes);
        int cells = B * SGRID3;
        prep_kernel<<<(cells / 4 + 255) / 256, 256, 0, stream>>>(output, closest,
                                                                 tbl, mats, out, B);
        int threads = 256;
        int quadsPerBatch = (N + 3) / 4;
        int bpb = (quadsPerBatch + threads - 1) / threads;   // 128 for N=131072
        sym_loss_v7<<<B * bpb, threads, 0, stream>>>(tbl, mats, points, out,
                                                     N, B, bpb, 1.0f / (float)B);
    } else {
        zero_out_kernel<<<1, 1, 0, stream>>>(out);
        int gx = (N + 1023) / 1024;
        dim3 grid(gx, B);
        sym_loss_kernel<<<grid, 256, 0, stream>>>(output, points, closest, out,
                                                  N, 1.0f / (float)B);
    }
}

// Round 8
// 102.996 us; speedup vs baseline: 1.0253x; 1.0253x over previous
//
#include <hip/hip_runtime.h>

#define SGRID 32
#define SGRID3 (SGRID * SGRID * SGRID)   // 32768 cells
#define Q5 (31.0f / 32.0f)               // quantize scale
#define DQ5 (32.0f / 31.0f)              // dequantize scale

// Single fused kernel: per-block inline table quantization (closest -> u16
// 5:5:5 in 64 KB LDS), redundant per-block affine-mat build, R5-proven main
// loop (block=1024, one quad/thread, 2 blocks/CU). No workspace, no prep
// dispatch. R4 lesson: no min-waves launch bound (spill). R7 lesson: don't
// shrink block size (staging/work ratio and waves/CU both degrade).
__global__ __launch_bounds__(1024)
void sym_loss_fused(const float* __restrict__ output,
                    const float* __restrict__ points,
                    const float* __restrict__ closest,
                    float* __restrict__ out,
                    int N, int B, int bpb, float invB) {
    __shared__ unsigned short sT[SGRID3];   // 64 KB
    __shared__ float sred[16];

    const int i = blockIdx.x;
    int b, x;
    if (B == 16 && (gridDim.x & 15) == 0) {
        // XCD swizzle: block i lands on XCD i%8 -> 2 batches per XCD in L2
        b = 2 * (i & 7) + ((i >> 3) & 1);
        x = i >> 4;
    } else {
        b = i / bpb;
        x = i - b * bpb;
    }

    // ---- affine mats, computed redundantly by every thread (wave-uniform) --
    const float* prm = output + (size_t)b * 24;
    float M[72];
#pragma unroll
    for (int r = 0; r < 3; r++) {           // reflections
        float a = prm[r * 4 + 0], bb = prm[r * 4 + 1];
        float c = prm[r * 4 + 2], d = prm[r * 4 + 3];
        float k = -2.f / (a * a + bb * bb + c * c);
        float* m = &M[r * 12];
        m[0] = 1.f + k * a * a;  m[1] = k * a * bb;        m[2] = k * a * c;        m[3] = k * d * a;
        m[4] = k * bb * a;       m[5] = 1.f + k * bb * bb; m[6] = k * bb * c;       m[7] = k * d * bb;
        m[8] = k * c * a;        m[9] = k * c * bb;        m[10] = 1.f + k * c * c; m[11] = k * d * c;
    }
#pragma unroll
    for (int r = 0; r < 3; r++) {           // rotations (q p q^-1, |q| folded)
        float w = prm[12 + r * 4 + 0], qx = prm[12 + r * 4 + 1];
        float qy = prm[12 + r * 4 + 2], qz = prm[12 + r * 4 + 3];
        float s = rsqrtf(w * w + qx * qx + qy * qy + qz * qz);
        float* m = &M[36 + r * 12];
        m[0] = s * (w * w + qx * qx - qy * qy - qz * qz);
        m[1] = s * 2.f * (qx * qy - w * qz);
        m[2] = s * 2.f * (qx * qz + w * qy);
        m[3] = 0.f;
        m[4] = s * 2.f * (qx * qy + w * qz);
        m[5] = s * (w * w - qx * qx + qy * qy - qz * qz);
        m[6] = s * 2.f * (qy * qz - w * qx);
        m[7] = 0.f;
        m[8] = s * 2.f * (qx * qz - w * qy);
        m[9] = s * 2.f * (qy * qz + w * qx);
        m[10] = s * (w * w - qx * qx - qy * qy + qz * qz);
        m[11] = 0.f;
    }

    // ---- stage + quantize table: 8192 cell-quads over 1024 threads ---------
    {
        const float4* src = (const float4*)(closest + (size_t)b * SGRID3 * 3);
        ushort4* dst = (ushort4*)sT;
#pragma unroll
        for (int j = 0; j < 8; j++) {
            int idx = j * 1024 + (int)threadIdx.x;     // quad-cell index
            float4 a = src[(size_t)idx * 3 + 0];
            float4 e = src[(size_t)idx * 3 + 1];
            float4 c = src[(size_t)idx * 3 + 2];
            float cx[4] = {a.x, a.w, e.z, c.y};
            float cy[4] = {a.y, e.x, e.w, c.z};
            float cz[4] = {a.z, e.y, c.x, c.w};
            ushort4 qv;
            unsigned short* qp = (unsigned short*)&qv;
#pragma unroll
            for (int k = 0; k < 4; k++) {
                unsigned int ux = min((unsigned int)(fmaxf(cx[k], 0.f) * Q5 + 0.5f), 31u);
                unsigned int uy = min((unsigned int)(fmaxf(cy[k], 0.f) * Q5 + 0.5f), 31u);
                unsigned int uz = min((unsigned int)(fmaxf(cz[k], 0.f) * Q5 + 0.5f), 31u);
                qp[k] = (unsigned short)(ux | (uy << 5) | (uz << 10));
            }
            dst[idx] = qv;
        }
    }
    __syncthreads();

    // ---- main loop: one quad (4 consecutive points = 3 float4) per thread --
    const float* pb = points + (size_t)b * N * 3;
    const float4* pv = (const float4*)pb;
    float acc = 0.f;

    const int q = x * (int)blockDim.x + (int)threadIdx.x;
    const int base = q * 4;
    if (base + 3 < N) {
        float4 v0 = pv[(size_t)q * 3 + 0];
        float4 v1 = pv[(size_t)q * 3 + 1];
        float4 v2 = pv[(size_t)q * 3 + 2];
        float px[4] = {v0.x, v0.w, v1.z, v2.y};
        float py[4] = {v0.y, v1.x, v1.w, v2.z};
        float pz[4] = {v0.z, v1.y, v2.x, v2.w};
#pragma unroll 2
        for (int k = 0; k < 4; k++) {
            float X = px[k], Y = py[k], Z = pz[k];
            float sx[6], sy[6], sz[6];
            unsigned int g[6];
#pragma unroll
            for (int op = 0; op < 6; op++) {
                const float* m = &M[op * 12];
                sx[op] = fmaf(m[0], X, fmaf(m[1], Y, fmaf(m[2], Z, m[3])));
                sy[op] = fmaf(m[4], X, fmaf(m[5], Y, fmaf(m[6], Z, m[7])));
                sz[op] = fmaf(m[8], X, fmaf(m[9], Y, fmaf(m[10], Z, m[11])));
                int ix = min(max((int)sx[op], 0), 31);   // v_cvt + v_med3_i32
                int iy = min(max((int)sy[op], 0), 31);
                int iz = min(max((int)sz[op], 0), 31);
                g[op] = sT[(ix << 10) | (iy << 5) | iz];
            }
#pragma unroll
            for (int op = 0; op < 6; op++) {
                float gx = (float)(g[op] & 31u);
                float gy = (float)((g[op] >> 5) & 31u);
                float gz = (float)(g[op] >> 10);
                float dx = fmaf(-DQ5, gx, sx[op]);
                float dy = fmaf(-DQ5, gy, sy[op]);
                float dz = fmaf(-DQ5, gz, sz[op]);
                acc += __builtin_amdgcn_sqrtf(fmaf(dx, dx, fmaf(dy, dy, dz * dz)));
            }
        }
    } else if (base < N) {
        for (int k = 0; k < N - base; k++) {
            float X = pb[(size_t)(base + k) * 3 + 0];
            float Y = pb[(size_t)(base + k) * 3 + 1];
            float Z = pb[(size_t)(base + k) * 3 + 2];
#pragma unroll
            for (int op = 0; op < 6; op++) {
                const float* m = &M[op * 12];
                float ssx = fmaf(m[0], X, fmaf(m[1], Y, fmaf(m[2], Z, m[3])));
                float ssy = fmaf(m[4], X, fmaf(m[5], Y, fmaf(m[6], Z, m[7])));
                float ssz = fmaf(m[8], X, fmaf(m[9], Y, fmaf(m[10], Z, m[11])));
                int ix = min(max((int)ssx, 0), 31);
                int iy = min(max((int)ssy, 0), 31);
                int iz = min(max((int)ssz, 0), 31);
                unsigned int gg = sT[(ix << 10) | (iy << 5) | iz];
                float gx = (float)(gg & 31u);
                float gy = (float)((gg >> 5) & 31u);
                float gz = (float)(gg >> 10);
                float dx = fmaf(-DQ5, gx, ssx);
                float dy = fmaf(-DQ5, gy, ssy);
                float dz = fmaf(-DQ5, gz, ssz);
                acc += __builtin_amdgcn_sqrtf(fmaf(dx, dx, fmaf(dy, dy, dz * dz)));
            }
        }
    }

    // ---- reduce: wave64 shuffle -> LDS -> one atomic per block -------------
#pragma unroll
    for (int off = 32; off > 0; off >>= 1)
        acc += __shfl_down(acc, off, 64);

    int lane = threadIdx.x & 63;
    int wid = threadIdx.x >> 6;
    if (lane == 0) sred[wid] = acc;
    __syncthreads();
    if (threadIdx.x == 0) {
        float s = 0.f;
#pragma unroll
        for (int w = 0; w < 16; w++) s += sred[w];
        atomicAdd(out, s * invB);
    }
}

extern "C" void kernel_launch(void* const* d_in, const int* in_sizes, int n_in,
                              void* d_out, int out_size, void* d_ws, size_t ws_size,
                              hipStream_t stream) {
    const float* output = (const float*)d_in[0];
    const float* points = (const float*)d_in[1];
    const float* closest = (const float*)d_in[2];
    float* out = (float*)d_out;

    int B = in_sizes[0] / 24;
    int N = in_sizes[1] / (3 * B);

    hipMemsetAsync(d_out, 0, sizeof(float), stream);   // graph-capture safe

    int threads = 1024;
    int quadsPerBatch = (N + 3) / 4;
    int bpb = (quadsPerBatch + threads - 1) / threads;   // 32 for N=131072
    sym_loss_fused<<<B * bpb, threads, 0, stream>>>(output, points, closest, out,
                                                    N, B, bpb, 1.0f / (float)B);
}

// Round 9
// 91.542 us; speedup vs baseline: 1.1536x; 1.1251x over previous
//
#include <hip/hip_runtime.h>

#define SGRID 32
#define SGRID3 (SGRID * SGRID * SGRID)   // 32768 cells
#define Q5 (31.0f / 32.0f)               // quantize scale
#define DQ5 (32.0f / 31.0f)              // dequantize scale

// ------- prep: quantize closest -> 5:5:5 u16, build affine mats, zero out ----
__global__ __launch_bounds__(256)
void prep_kernel(const float* __restrict__ output,
                 const float* __restrict__ closest,
                 unsigned short* __restrict__ tbl,   // B * 32768 u16
                 float* __restrict__ mats,           // B * 72
                 float* __restrict__ out,
                 int B) {
    int tid = blockIdx.x * blockDim.x + threadIdx.x;
    int total = B * SGRID3;
    int base = tid * 4;
    if (base + 3 < total) {
        const float4* src = (const float4*)closest;  // 4 cells = 12 floats
        float4 a = src[(size_t)tid * 3 + 0];
        float4 b = src[(size_t)tid * 3 + 1];
        float4 c = src[(size_t)tid * 3 + 2];
        float cx[4] = {a.x, a.w, b.z, c.y};
        float cy[4] = {a.y, b.x, b.w, c.z};
        float cz[4] = {a.z, b.y, c.x, c.w};
        ushort4 q;
        unsigned short* qp = (unsigned short*)&q;
#pragma unroll
        for (int k = 0; k < 4; k++) {
            unsigned int qx = min((unsigned int)(fmaxf(cx[k], 0.f) * Q5 + 0.5f), 31u);
            unsigned int qy = min((unsigned int)(fmaxf(cy[k], 0.f) * Q5 + 0.5f), 31u);
            unsigned int qz = min((unsigned int)(fmaxf(cz[k], 0.f) * Q5 + 0.5f), 31u);
            qp[k] = (unsigned short)(qx | (qy << 5) | (qz << 10));
        }
        *((ushort4*)(tbl + base)) = q;
    }
    if (blockIdx.x == 0) {
        if (threadIdx.x == 0) out[0] = 0.f;
        if (threadIdx.x < B * 6) {
            int b = threadIdx.x / 6, i = threadIdx.x % 6;
            const float* p = output + b * 24 + i * 4;
            float m[12];
            if (i < 3) {
                float a = p[0], bb = p[1], c = p[2], d = p[3];
                float k = -2.f / (a * a + bb * bb + c * c);
                m[0] = 1.f + k * a * a;  m[1] = k * a * bb;        m[2] = k * a * c;        m[3] = k * d * a;
                m[4] = k * bb * a;       m[5] = 1.f + k * bb * bb; m[6] = k * bb * c;       m[7] = k * d * bb;
                m[8] = k * c * a;        m[9] = k * c * bb;        m[10] = 1.f + k * c * c; m[11] = k * d * c;
            } else {
                float w = p[0], x = p[1], y = p[2], z = p[3];
                float s = rsqrtf(w * w + x * x + y * y + z * z);
                m[0] = s * (w * w + x * x - y * y - z * z);
                m[1] = s * 2.f * (x * y - w * z);
                m[2] = s * 2.f * (x * z + w * y);
                m[3] = 0.f;
                m[4] = s * 2.f * (x * y + w * z);
                m[5] = s * (w * w - x * x + y * y - z * z);
                m[6] = s * 2.f * (y * z - w * x);
                m[7] = 0.f;
                m[8] = s * 2.f * (x * z - w * y);
                m[9] = s * 2.f * (y * z + w * x);
                m[10] = s * (w * w - x * x - y * y + z * z);
                m[11] = 0.f;
            }
            float* dst = mats + (size_t)threadIdx.x * 12;
#pragma unroll
            for (int j = 0; j < 12; j++) dst[j] = m[j];
        }
    }
}

// ------- main: 64 KB u16 table, grid=256 (1 block/CU), 2 quads/thread -------
// Staging traffic = grid x 64 KB: grid 256 halves it vs R5's 512 (R7/R8
// lesson: this term dominates deltas). Inner loop is R5's proven 6-window.
// No min-waves bound (R4 spill lesson).
__global__ __launch_bounds__(1024)
void sym_loss_v9(const unsigned short* __restrict__ tbl,
                 const float* __restrict__ mats,
                 const float* __restrict__ points,
                 float* __restrict__ out,
                 int N, int B, int bpb, float invB) {
    __shared__ unsigned short sT[SGRID3];   // 64 KB
    __shared__ float sred[16];

    const int i = blockIdx.x;
    int b, x;
    if (B == 16 && (gridDim.x & 15) == 0) {
        // XCD swizzle: block i lands on XCD i%8 -> 2 batches per XCD in L2
        b = 2 * (i & 7) + ((i >> 3) & 1);
        x = i >> 4;
    } else {
        b = i / bpb;
        x = i - b * bpb;
    }

    // stage 64 KB: 4096 uint4 across 1024 threads = 4 x 16B each
    {
        const uint4* src = (const uint4*)(tbl + (size_t)b * SGRID3);
        uint4* dst = (uint4*)sT;
#pragma unroll
        for (int j = 0; j < 4; j++)
            dst[j * 1024 + threadIdx.x] = src[j * 1024 + threadIdx.x];
    }

    // wave-uniform affine mats (6 x 3x4) -> SGPRs
    const float* mb = mats + (size_t)b * 72;
    float M[72];
#pragma unroll
    for (int j = 0; j < 72; j++) M[j] = mb[j];

    __syncthreads();

    const float* pb = points + (size_t)b * N * 3;
    const float4* pv = (const float4*)pb;
    float acc = 0.f;

    // two quads per thread, both point-loads issued up front (ILP)
    const int q0 = x * 2 * (int)blockDim.x + (int)threadIdx.x;
    const int q1 = q0 + (int)blockDim.x;

#pragma unroll
    for (int pass = 0; pass < 2; pass++) {
        int q = pass ? q1 : q0;
        int base = q * 4;
        if (base + 3 < N) {
            float4 v0 = pv[(size_t)q * 3 + 0];
            float4 v1 = pv[(size_t)q * 3 + 1];
            float4 v2 = pv[(size_t)q * 3 + 2];
            float px[4] = {v0.x, v0.w, v1.z, v2.y};
            float py[4] = {v0.y, v1.x, v1.w, v2.z};
            float pz[4] = {v0.z, v1.y, v2.x, v2.w};
#pragma unroll 2
            for (int k = 0; k < 4; k++) {
                float X = px[k], Y = py[k], Z = pz[k];
                float sx[6], sy[6], sz[6];
                unsigned int g[6];
#pragma unroll
                for (int op = 0; op < 6; op++) {
                    const float* m = &M[op * 12];
                    sx[op] = fmaf(m[0], X, fmaf(m[1], Y, fmaf(m[2], Z, m[3])));
                    sy[op] = fmaf(m[4], X, fmaf(m[5], Y, fmaf(m[6], Z, m[7])));
                    sz[op] = fmaf(m[8], X, fmaf(m[9], Y, fmaf(m[10], Z, m[11])));
                    int ix = min(max((int)sx[op], 0), 31);   // v_cvt + v_med3_i32
                    int iy = min(max((int)sy[op], 0), 31);
                    int iz = min(max((int)sz[op], 0), 31);
                    g[op] = sT[(ix << 10) | (iy << 5) | iz];
                }
#pragma unroll
                for (int op = 0; op < 6; op++) {
                    float gx = (float)(g[op] & 31u);
                    float gy = (float)((g[op] >> 5) & 31u);
                    float gz = (float)(g[op] >> 10);
                    float dx = fmaf(-DQ5, gx, sx[op]);
                    float dy = fmaf(-DQ5, gy, sy[op]);
                    float dz = fmaf(-DQ5, gz, sz[op]);
                    acc += __builtin_amdgcn_sqrtf(fmaf(dx, dx, fmaf(dy, dy, dz * dz)));
                }
            }
        } else if (base < N) {
            for (int k = 0; k < N - base; k++) {
                float X = pb[(size_t)(base + k) * 3 + 0];
                float Y = pb[(size_t)(base + k) * 3 + 1];
                float Z = pb[(size_t)(base + k) * 3 + 2];
#pragma unroll
                for (int op = 0; op < 6; op++) {
                    const float* m = &M[op * 12];
                    float ssx = fmaf(m[0], X, fmaf(m[1], Y, fmaf(m[2], Z, m[3])));
                    float ssy = fmaf(m[4], X, fmaf(m[5], Y, fmaf(m[6], Z, m[7])));
                    float ssz = fmaf(m[8], X, fmaf(m[9], Y, fmaf(m[10], Z, m[11])));
                    int ix = min(max((int)ssx, 0), 31);
                    int iy = min(max((int)ssy, 0), 31);
                    int iz = min(max((int)ssz, 0), 31);
                    unsigned int gg = sT[(ix << 10) | (iy << 5) | iz];
                    float gx = (float)(gg & 31u);
                    float gy = (float)((gg >> 5) & 31u);
                    float gz = (float)(gg >> 10);
                    float dx = fmaf(-DQ5, gx, ssx);
                    float dy = fmaf(-DQ5, gy, ssy);
                    float dz = fmaf(-DQ5, gz, ssz);
                    acc += __builtin_amdgcn_sqrtf(fmaf(dx, dx, fmaf(dy, dy, dz * dz)));
                }
            }
        }
    }

    // reduce: wave64 shuffle -> LDS -> one atomic per block
#pragma unroll
    for (int off = 32; off > 0; off >>= 1)
        acc += __shfl_down(acc, off, 64);

    int lane = threadIdx.x & 63;
    int wid = threadIdx.x >> 6;
    if (lane == 0) sred[wid] = acc;
    __syncthreads();
    if (threadIdx.x == 0) {
        float s = 0.f;
#pragma unroll
        for (int w = 0; w < 16; w++) s += sred[w];
        atomicAdd(out, s * invB);
    }
}

// ------- fallback (ws too small): direct-gather kernel ----------------------
__global__ void zero_out_kernel(float* out) { out[0] = 0.0f; }

__launch_bounds__(256)
__global__ void sym_loss_kernel(const float* __restrict__ output,
                                const float* __restrict__ points,
                                const float* __restrict__ closest,
                                float* __restrict__ out,
                                int N, float invB) {
    const int b = blockIdx.y;
    const int tid = blockIdx.x * blockDim.x + threadIdx.x;
    const float* prm = output + (size_t)b * 24;
    float pn[3][4], inv_nn[3], qt[3][4], qinvn[3];
#pragma unroll
    for (int i = 0; i < 3; i++) {
        pn[i][0] = prm[i * 4 + 0]; pn[i][1] = prm[i * 4 + 1];
        pn[i][2] = prm[i * 4 + 2]; pn[i][3] = prm[i * 4 + 3];
        inv_nn[i] = 1.0f / (pn[i][0] * pn[i][0] + pn[i][1] * pn[i][1] + pn[i][2] * pn[i][2]);
        qt[i][0] = prm[12 + i * 4 + 0]; qt[i][1] = prm[12 + i * 4 + 1];
        qt[i][2] = prm[12 + i * 4 + 2]; qt[i][3] = prm[12 + i * 4 + 3];
        qinvn[i] = rsqrtf(qt[i][0] * qt[i][0] + qt[i][1] * qt[i][1] +
                          qt[i][2] * qt[i][2] + qt[i][3] * qt[i][3]);
    }
    const float* pb = points + (size_t)b * N * 3;
    const float* cb = closest + (size_t)b * SGRID3 * 3;
    float acc = 0.0f;
    const int base = tid * 4;
    float px[4], py[4], pz[4];
    int npts = 0;
    if (base + 3 < N) {
        const float4* pv = (const float4*)pb;
        float4 v0 = pv[(size_t)tid * 3 + 0];
        float4 v1 = pv[(size_t)tid * 3 + 1];
        float4 v2 = pv[(size_t)tid * 3 + 2];
        px[0] = v0.x; py[0] = v0.y; pz[0] = v0.z;
        px[1] = v0.w; py[1] = v1.x; pz[1] = v1.y;
        px[2] = v1.z; py[2] = v1.w; pz[2] = v2.x;
        px[3] = v2.y; py[3] = v2.z; pz[3] = v2.w;
        npts = 4;
    } else if (base < N) {
        npts = N - base;
        for (int k = 0; k < npts; k++) {
            px[k] = pb[(size_t)(base + k) * 3 + 0];
            py[k] = pb[(size_t)(base + k) * 3 + 1];
            pz[k] = pb[(size_t)(base + k) * 3 + 2];
        }
    }
#pragma unroll
    for (int k = 0; k < 4; k++) {
        if (k >= npts) break;
        float x = px[k], y = py[k], z = pz[k];
#pragma unroll
        for (int i = 0; i < 3; i++) {
            float nx = pn[i][0], ny = pn[i][1], nz = pn[i][2];
            float dis = (nx * x + ny * y + nz * z + pn[i][3]) * inv_nn[i];
            float t = 2.0f * dis;
            float sx = x - t * nx, sy = y - t * ny, sz = z - t * nz;
            int ix = min(max((int)fminf(sx, 32.f), 0), 31);
            int iy = min(max((int)fminf(sy, 32.f), 0), 31);
            int iz = min(max((int)fminf(sz, 32.f), 0), 31);
            const float* c = cb + (size_t)((ix << 10) | (iy << 5) | iz) * 3;
            float dx = sx - c[0], dy = sy - c[1], dz = sz - c[2];
            acc += __builtin_amdgcn_sqrtf(fmaf(dx, dx, fmaf(dy, dy, dz * dz)));
        }
#pragma unroll
        for (int i = 0; i < 3; i++) {
            float rw = qt[i][0], rx = qt[i][1], ry = qt[i][2], rz = qt[i][3];
            float tw = -(rx * x + ry * y + rz * z);
            float tx = rw * x + (ry * z - rz * y);
            float ty = rw * y + (rz * x - rx * z);
            float tz = rw * z + (rx * y - ry * x);
            float n = qinvn[i];
            float ox = (-tw * rx + rw * tx + (ry * tz - rz * ty)) * n;
            float oy = (-tw * ry + rw * ty + (rz * tx - rx * tz)) * n;
            float oz = (-tw * rz + rw * tz + (rx * ty - ry * tx)) * n;
            int ix = min(max((int)fminf(ox, 32.f), 0), 31);
            int iy = min(max((int)fminf(oy, 32.f), 0), 31);
            int iz = min(max((int)fminf(oz, 32.f), 0), 31);
            const float* c = cb + (size_t)((ix << 10) | (iy << 5) | iz) * 3;
            float dx = ox - c[0], dy = oy - c[1], dz = oz - c[2];
            acc += __builtin_amdgcn_sqrtf(fmaf(dx, dx, fmaf(dy, dy, dz * dz)));
        }
    }
#pragma unroll
    for (int off = 32; off > 0; off >>= 1)
        acc += __shfl_down(acc, off, 64);
    __shared__ float sacc[4];
    int lane = threadIdx.x & 63;
    int wid = threadIdx.x >> 6;
    if (lane == 0) sacc[wid] = acc;
    __syncthreads();
    if (threadIdx.x == 0)
        atomicAdd(out, (sacc[0] + sacc[1] + sacc[2] + sacc[3]) * invB);
}

extern "C" void kernel_launch(void* const* d_in, const int* in_sizes, int n_in,
                              void* d_out, int out_size, void* d_ws, size_t ws_size,
                              hipStream_t stream) {
    const float* output = (const float*)d_in[0];
    const float* points = (const float*)d_in[1];
    const float* closest = (const float*)d_in[2];
    float* out = (float*)d_out;

    int B = in_sizes[0] / 24;
    int N = in_sizes[1] / (3 * B);

    size_t tbl_bytes = (size_t)B * SGRID3 * 2;
    size_t mats_bytes = (size_t)B * 72 * 4;

    if (ws_size >= tbl_bytes + mats_bytes) {
        unsigned short* tbl = (unsigned short*)d_ws;
        float* mats = (float*)((char*)d_ws + tbl_bytes);
        int cells = B * SGRID3;
        prep_kernel<<<(cells / 4 + 255) / 256, 256, 0, stream>>>(output, closest,
                                                                 tbl, mats, out, B);
        int threads = 1024;
        int quadsPerBatch = (N + 3) / 4;
        int qpb = threads * 2;                         // quads per block
        int bpb = (quadsPerBatch + qpb - 1) / qpb;     // 16 for N=131072
        sym_loss_v9<<<B * bpb, threads, 0, stream>>>(tbl, mats, points, out,
                                                     N, B, bpb, 1.0f / (float)B);
    } else {
        zero_out_kernel<<<1, 1, 0, stream>>>(out);
        int gx = (N + 1023) / 1024;
        dim3 grid(gx, B);
        sym_loss_kernel<<<grid, 256, 0, stream>>>(output, points, closest, out,
                                                  N, 1.0f / (float)B);
    }
}